// Round 5
// baseline (17606.488 us; speedup 1.0000x reference)
//
#include <hip/hip_runtime.h>
#include <hip/hip_bf16.h>

#define T_STEPS 1024
#define NWG     16

typedef __attribute__((ext_vector_type(8))) short          bf16x8;
typedef __attribute__((ext_vector_type(4))) float          f32x4;
typedef __attribute__((ext_vector_type(8))) unsigned short u16x8;

static __device__ __forceinline__ unsigned short f2bf_bits(float f) {
    union { __hip_bfloat16 h; unsigned short u; } cv;
    cv.h = __float2bfloat16(f);
    return cv.u;
}

// ---------------------------------------------------------------------------
// P1: fold ln_g into weights, cast bf16, emit in MFMA B-fragment order.
// Block = (g, kq, ng): blk = ((g*4+kq)*2+ng), 128 blocks x 256 thr.
// Chunk [g][kq][ng]: [nt(4)][kstep(8)][lane(64)][e(8)] bf16 (32 KB).
//   gate col n = q*512 + g*32 + c, where cc = ng*64 + nt*16 + (lane&15),
//                q = cc>>5, c = cc&31
//   k = kq*256 + kstep*32 + (lane>>4)*8 + e   (k<512: x rows, else h rows)
// ---------------------------------------------------------------------------
__global__ __launch_bounds__(256) void pack_weights(
    const float* __restrict__ Wf, const float* __restrict__ Wi,
    const float* __restrict__ Wg, const float* __restrict__ Wo,
    const float* __restrict__ ln_g, __hip_bfloat16* __restrict__ pack)
{
    __shared__ float tile[256][64];   // [k_local][c64] (c64 = local col in ng half)
    const int blk = blockIdx.x;
    const int g = blk >> 3, kq = (blk >> 1) & 3, ng = blk & 1;
    const int tid = threadIdx.x;

    for (int idx = tid; idx < 256 * 64; idx += 256) {
        int kl = idx >> 6, c64 = idx & 63;
        int q = ng * 2 + (c64 >> 5);
        int j = g * 32 + (c64 & 31);
        int k = kq * 256 + kl;
        const float* W = (q == 0) ? Wf : ((q == 1) ? Wi : ((q == 2) ? Wg : Wo));
        tile[kl][c64] = W[k * 512 + j] * ln_g[k];
    }
    __syncthreads();

    unsigned short* out = (unsigned short*)(pack + (size_t)blk * 16384);
    for (int s = tid; s < 2048; s += 256) {     // s = (nt*8 + ks)*64 + l
        int nt = s >> 9, ks = (s >> 6) & 7, l = s & 63;
        u16x8 v;
#pragma unroll
        for (int e = 0; e < 8; ++e) {
            int kl = ks * 32 + (l >> 4) * 8 + e;
            int c64 = nt * 16 + (l & 15);
            v[e] = f2bf_bits(tile[kl][c64]);
        }
        *(u16x8*)(out + (size_t)s * 8) = v;
    }
}

// ---------------------------------------------------------------------------
// P2: S[n] = sum_k ln_g[k]*W[k,n],  C[n] = sum_k ln_b[k]*W[k,n] + bias[n]
// ---------------------------------------------------------------------------
__global__ __launch_bounds__(256) void compute_sc(
    const float* __restrict__ Wf, const float* __restrict__ Wi,
    const float* __restrict__ Wg, const float* __restrict__ Wo,
    const float* __restrict__ bf_, const float* __restrict__ bi_,
    const float* __restrict__ bg_, const float* __restrict__ bo_,
    const float* __restrict__ ln_g, const float* __restrict__ ln_b,
    float* __restrict__ S, float* __restrict__ C)
{
    int n = blockIdx.x * 256 + threadIdx.x;        // 0..2047
    int q = n >> 9, j = n & 511;
    const float* W = (q == 0) ? Wf : ((q == 1) ? Wi : ((q == 2) ? Wg : Wo));
    const float* bb = (q == 0) ? bf_ : ((q == 1) ? bi_ : ((q == 2) ? bg_ : bo_));
    float accS = 0.f, accC = 0.f;
    for (int k = 0; k < 1024; ++k) {
        float w = W[k * 512 + j];
        accS += ln_g[k] * w;
        accC += ln_b[k] * w;
    }
    S[n] = accS;
    C[n] = accC + bb[j];
}

// ---------------------------------------------------------------------------
// P3: x -> bf16 copy + per-row sum / sumsq (fp32). One wave per (t,b) row.
// ---------------------------------------------------------------------------
__global__ __launch_bounds__(256) void prep_x(
    const float* __restrict__ x, __hip_bfloat16* __restrict__ xb,
    float* __restrict__ sx, float* __restrict__ sq)
{
    const int wave = threadIdx.x >> 6, lane = threadIdx.x & 63;
    const long row = (long)blockIdx.x * 4 + wave;  // 0..65535
    const float* src = x + row * 512 + lane * 8;
    float4 a = *(const float4*)src;
    float4 b = *(const float4*)(src + 4);
    float vals[8] = {a.x, a.y, a.z, a.w, b.x, b.y, b.z, b.w};
    u16x8 o;
    float s = 0.f, qq = 0.f;
#pragma unroll
    for (int e = 0; e < 8; ++e) {
        s += vals[e];
        qq += vals[e] * vals[e];
        o[e] = f2bf_bits(vals[e]);
    }
    *(u16x8*)((unsigned short*)xb + row * 512 + lane * 8) = o;
#pragma unroll
    for (int d = 1; d < 64; d <<= 1) {
        s  += __shfl_xor(s, d);
        qq += __shfl_xor(qq, d);
    }
    if (lane == 0) { sx[row] = s; sq[row] = qq; }
}

// ---------------------------------------------------------------------------
// Main persistent kernel: 16 WGs x 512 threads. WG g owns h-cols
// [g*32, g*32+32) (= 128 gate cols). Wave w: kq = w>>1 (K quarter of 1024),
// ng = w&1 (64-gate-col half). kq<2: x-waves (shadow GEMM for t+1, regs
// persist); kq>=2: h-waves (critical h-GEMM). Weights register-resident,
// zero replication (128 VGPR B-frags per wave).
// Sync: per-WG flag; consumers poll with per-lane DIVERGENT spin on line
// (lane&15) only (incremental — done lanes mask off). Publish = plain sc1
// stores + vmcnt(0) + barrier + wave0 flag. Stats: exact fp32 psc partials.
// Gates: thread (b = tid>>3, jl = tid&7) owns 4 h-cols jl*4..jl*4+4 of row b.
// ---------------------------------------------------------------------------
__global__ __launch_bounds__(512, 2) void qlstm_main(
    const float* __restrict__ x,
    const __hip_bfloat16* __restrict__ pack,
    const float* __restrict__ Sarr, const float* __restrict__ Carr,
    const __hip_bfloat16* __restrict__ xb,
    const float* __restrict__ sx, const float* __restrict__ sq,
    unsigned short* __restrict__ hxb,   // [2][64][512] bf16 (zeroed)
    float2* __restrict__ psc,           // [2][16][64] float2 (zeroed)
    unsigned int* __restrict__ flags,   // [16] spaced 16 u32 (zeroed)
    float* __restrict__ out)            // stacked | hx | cx (fp32)
{
    const int g = blockIdx.x;
    const int tid = threadIdx.x;
    const int wave = tid >> 6, lane = tid & 63;
    const int kq = wave >> 1, ng = wave & 1;
    const bool isH = (kq >= 2);
    const int b = tid >> 3, jl = tid & 7;
    const int jg0 = g * 32 + jl * 4;

    __shared__ __align__(16) float zX[2][64][132];
    __shared__ __align__(16) float zH[2][64][132];
    __shared__ float2 hsum[64];
    __shared__ float Scol[128], Ccol[128];

    if (tid < 128) {
        int q = tid >> 5, c = tid & 31;
        int n = q * 512 + g * 32 + c;
        Scol[tid] = Sarr[n];
        Ccol[tid] = Carr[n];
    }

    // Register-resident B-fragments: 4 n-tiles x 8 ksteps x 16B = 128 VGPR.
    bf16x8 Bf[4][8];
    {
        const bf16x8* pb = (const bf16x8*)pack + (size_t)((g * 4 + kq) * 2 + ng) * 2048;
#pragma unroll
        for (int nt = 0; nt < 4; ++nt)
#pragma unroll
            for (int ks = 0; ks < 8; ++ks)
                Bf[nt][ks] = pb[(nt * 8 + ks) * 64 + lane];
    }

    const int lrow = lane & 15, lkb = (lane >> 4) * 8;
    const int r0l = (lane >> 4) * 4, c0 = lane & 15;

    f32x4 acc[4][4];
    float cx[4] = {0.f, 0.f, 0.f, 0.f};

    // pre-loop: x-waves compute x-GEMM for t=0 into persistent acc
    if (!isH) {
#pragma unroll
        for (int m = 0; m < 4; ++m) {
#pragma unroll
            for (int nt = 0; nt < 4; ++nt) acc[m][nt] = (f32x4){0.f, 0.f, 0.f, 0.f};
            const bf16x8* Ap = (const bf16x8*)(xb + (size_t)(m * 16 + lrow) * 512
                                               + kq * 256 + lkb);
#pragma unroll
            for (int ks = 0; ks < 8; ++ks) {
                bf16x8 a = Ap[ks * 4];
#pragma unroll
                for (int nt = 0; nt < 4; ++nt)
                    acc[m][nt] = __builtin_amdgcn_mfma_f32_16x16x32_bf16(a, Bf[nt][ks], acc[m][nt], 0, 0, 0);
            }
        }
    }

    for (int t = 0; t < T_STEPS; ++t) {
        const int p = t & 1;

        // recurrence-independent loads
        float sxv = sx[t * 64 + b], sqv = sq[t * 64 + b];
        float4 xr = *(const float4*)(x + (size_t)t * 32768 + b * 512 + jg0);

        if (isH) {
            // ---- incremental divergent spin: lane polls ONLY line (lane&15) ----
            if (t) {
                const unsigned int* fp_ = flags + ((lane & 15) << 4);
                unsigned f;
                do {
                    f = __hip_atomic_load(fp_, __ATOMIC_RELAXED, __HIP_MEMORY_SCOPE_AGENT);
                } while ((int)f < t);
                asm volatile("" ::: "memory");
            }
            const int kql = kq - 2;
            const unsigned long long* hp =
                (const unsigned long long*)hxb + (size_t)p * 8192;
#pragma unroll
            for (int m = 0; m < 4; ++m) {
#pragma unroll
                for (int nt = 0; nt < 4; ++nt) acc[m][nt] = (f32x4){0.f, 0.f, 0.f, 0.f};
                const int ebase = ((m * 16 + lrow) * 512 + kql * 256 + lkb) >> 2;
                unsigned long long w0[8], w1[8];
#pragma unroll
                for (int ks = 0; ks < 8; ++ks) {
                    w0[ks] = __hip_atomic_load(hp + ebase + ks * 8,
                                               __ATOMIC_RELAXED, __HIP_MEMORY_SCOPE_AGENT);
                    w1[ks] = __hip_atomic_load(hp + ebase + ks * 8 + 1,
                                               __ATOMIC_RELAXED, __HIP_MEMORY_SCOPE_AGENT);
                }
#pragma unroll
                for (int ks = 0; ks < 8; ++ks) {
                    union { unsigned long long u[2]; bf16x8 v; } cv;
                    cv.u[0] = w0[ks]; cv.u[1] = w1[ks];
#pragma unroll
                    for (int nt = 0; nt < 4; ++nt)
                        acc[m][nt] = __builtin_amdgcn_mfma_f32_16x16x32_bf16(cv.v, Bf[nt][ks], acc[m][nt], 0, 0, 0);
                }
#pragma unroll
                for (int nt = 0; nt < 4; ++nt)
#pragma unroll
                    for (int r = 0; r < 4; ++r)
                        zH[kql][m * 16 + r0l + r][ng * 64 + nt * 16 + c0] = acc[m][nt][r];
            }
        } else {
            // ---- wave0: gather psc partials -> hsum ----
            if (wave == 0) {
                if (t) {
                    const unsigned int* fp_ = flags + ((lane & 15) << 4);
                    unsigned f;
                    do {
                        f = __hip_atomic_load(fp_, __ATOMIC_RELAXED, __HIP_MEMORY_SCOPE_AGENT);
                    } while ((int)f < t);
                    asm volatile("" ::: "memory");
                }
                float hs = 0.f, hq = 0.f;
                const unsigned long long* pp =
                    (const unsigned long long*)(psc + (size_t)p * 1024);
#pragma unroll
                for (int s = 0; s < 16; ++s) {
                    unsigned long long v = __hip_atomic_load(pp + s * 64 + lane,
                                                             __ATOMIC_RELAXED, __HIP_MEMORY_SCOPE_AGENT);
                    union { unsigned long long u; float2 f; } cv; cv.u = v;
                    hs += cv.f.x; hq += cv.f.y;
                }
                hsum[lane] = make_float2(hs, hq);
            }
            // ---- dump zX(t) from persistent acc ----
#pragma unroll
            for (int m = 0; m < 4; ++m)
#pragma unroll
                for (int nt = 0; nt < 4; ++nt)
#pragma unroll
                    for (int r = 0; r < 4; ++r)
                        zX[kq][m * 16 + r0l + r][ng * 64 + nt * 16 + c0] = acc[m][nt][r];
            // ---- x-GEMM for t+1 (shadow) ----
            if (t + 1 < T_STEPS) {
#pragma unroll
                for (int m = 0; m < 4; ++m) {
#pragma unroll
                    for (int nt = 0; nt < 4; ++nt) acc[m][nt] = (f32x4){0.f, 0.f, 0.f, 0.f};
                    const bf16x8* Ap = (const bf16x8*)(xb + (size_t)(t + 1) * 32768
                                                       + (m * 16 + lrow) * 512 + kq * 256 + lkb);
#pragma unroll
                    for (int ks = 0; ks < 8; ++ks) {
                        bf16x8 a = Ap[ks * 4];
#pragma unroll
                        for (int nt = 0; nt < 4; ++nt)
                            acc[m][nt] = __builtin_amdgcn_mfma_f32_16x16x32_bf16(a, Bf[nt][ks], acc[m][nt], 0, 0, 0);
                    }
                }
            }
        }
        __syncthreads();   // barrier A: zX, zH, hsum ready

        // ---- gates / state update: thread owns (b, cols jg0..jg0+4) ----
        float hval[4];
        {
            float2 hsb = hsum[b];
            float mu = (sxv + hsb.x) * (1.f / 1024.f);
            float var = (sqv + hsb.y) * (1.f / 1024.f) - mu * mu;
            float rs = rsqrtf(var + 1e-5f);

            float zqv[4][4];
#pragma unroll
            for (int q = 0; q < 4; ++q) {
                const int o = q * 32 + jl * 4;
                float4 a0 = *(const float4*)&zX[0][b][o];
                float4 a1 = *(const float4*)&zX[1][b][o];
                float4 a2 = *(const float4*)&zH[0][b][o];
                float4 a3 = *(const float4*)&zH[1][b][o];
                zqv[q][0] = a0.x + a1.x + a2.x + a3.x;
                zqv[q][1] = a0.y + a1.y + a2.y + a3.y;
                zqv[q][2] = a0.z + a1.z + a2.z + a3.z;
                zqv[q][3] = a0.w + a1.w + a2.w + a3.w;
            }
            float xrr[4] = {xr.x, xr.y, xr.z, xr.w};
#pragma unroll
            for (int d = 0; d < 4; ++d) {
                int jc = jl * 4 + d;
                float zf = rs * (zqv[0][d] - mu * Scol[jc])      + Ccol[jc];
                float zi = rs * (zqv[1][d] - mu * Scol[32 + jc]) + Ccol[32 + jc];
                float zg = rs * (zqv[2][d] - mu * Scol[64 + jc]) + Ccol[64 + jc];
                float zo = rs * (zqv[3][d] - mu * Scol[96 + jc]) + Ccol[96 + jc];
                float f  = 1.f / (1.f + __expf(-zf));
                float i_ = 1.f / (1.f + __expf(-zi));
                float gg = 2.f / (1.f + __expf(-2.f * zg)) - 1.f;
                float o_ = 1.f / (1.f + __expf(-zo));
                cx[d] = f * cx[d] + i_ * gg;
                float th = 2.f / (1.f + __expf(-2.f * cx[d])) - 1.f;
                hval[d] = o_ * th + xrr[d];
            }
        }

        // ---- publish h + psc (sc1 write-through), drain, flag ----
        if (t + 1 < T_STEPS) {
            union { unsigned short us[4]; unsigned long long u; } hb;
#pragma unroll
            for (int d = 0; d < 4; ++d) hb.us[d] = f2bf_bits(hval[d]);
            __hip_atomic_store(
                (unsigned long long*)(hxb + (size_t)(p ^ 1) * 32768 + b * 512 + jg0),
                hb.u, __ATOMIC_RELAXED, __HIP_MEMORY_SCOPE_AGENT);
            float s1 = hval[0] + hval[1] + hval[2] + hval[3];
            float q1 = hval[0] * hval[0] + hval[1] * hval[1]
                     + hval[2] * hval[2] + hval[3] * hval[3];
            s1 += __shfl_xor(s1, 1, 8); q1 += __shfl_xor(q1, 1, 8);
            s1 += __shfl_xor(s1, 2, 8); q1 += __shfl_xor(q1, 2, 8);
            s1 += __shfl_xor(s1, 4, 8); q1 += __shfl_xor(q1, 4, 8);
            if (jl == 0) {
                union { float2 f; unsigned long long u; } pv;
                pv.f = make_float2(s1, q1);
                __hip_atomic_store(
                    (unsigned long long*)(psc + (size_t)(p ^ 1) * 1024 + g * 64 + b),
                    pv.u, __ATOMIC_RELAXED, __HIP_MEMORY_SCOPE_AGENT);
            }
            asm volatile("s_waitcnt vmcnt(0)" ::: "memory");
        }
        __syncthreads();   // barrier B: all publishes drained, LDS reads done
        if (t + 1 < T_STEPS && tid == 0) {
            __hip_atomic_store(flags + g * 16, (unsigned)(t + 1),
                               __ATOMIC_RELAXED, __HIP_MEMORY_SCOPE_AGENT);
        }

        // ---- out writes (off sync path) ----
        *(float4*)(out + (size_t)t * 32768 + b * 512 + jg0) =
            make_float4(hval[0], hval[1], hval[2], hval[3]);
        if (t == T_STEPS - 1) {
            *(float4*)(out + (size_t)T_STEPS * 32768 + b * 512 + jg0) =
                make_float4(hval[0], hval[1], hval[2], hval[3]);
            *(float4*)(out + (size_t)T_STEPS * 32768 + 32768 + b * 512 + jg0) =
                make_float4(cx[0], cx[1], cx[2], cx[3]);
        }
    }
}

// ---------------------------------------------------------------------------
extern "C" void kernel_launch(void* const* d_in, const int* in_sizes, int n_in,
                              void* d_out, int out_size, void* d_ws, size_t ws_size,
                              hipStream_t stream)
{
    const float* x    = (const float*)d_in[0];
    const float* ln_g = (const float*)d_in[1];
    const float* ln_b = (const float*)d_in[2];
    const float* Wf   = (const float*)d_in[3];
    const float* bf_  = (const float*)d_in[4];
    const float* Wi   = (const float*)d_in[5];
    const float* bi_  = (const float*)d_in[6];
    const float* Wg   = (const float*)d_in[7];
    const float* bg_  = (const float*)d_in[8];
    const float* Wo   = (const float*)d_in[9];
    const float* bo_  = (const float*)d_in[10];

    char* ws = (char*)d_ws;
    size_t off = 0;
    auto take = [&](size_t bytes) -> char* {
        char* p = ws + off;
        off += (bytes + 255) & ~(size_t)255;
        return p;
    };
    __hip_bfloat16* pack = (__hip_bfloat16*)take((size_t)2097152 * 2); // 4 MB
    float* S             = (float*)take(2048 * 4);
    float* C             = (float*)take(2048 * 4);
    __hip_bfloat16* xb   = (__hip_bfloat16*)take((size_t)33554432 * 2); // 64 MB
    float* sx            = (float*)take(65536 * 4);
    float* sq            = (float*)take(65536 * 4);
    char* ctrl = ws + off;
    unsigned short* hxb  = (unsigned short*)take((size_t)2 * 64 * 512 * 2);  // 128 KB
    float2* psc          = (float2*)take((size_t)2 * 16 * 64 * 8);           // 16 KB
    unsigned int* flags  = (unsigned int*)take(16 * 16 * 4);                 // 1 KB
    size_t ctrl_bytes = (size_t)((ws + off) - ctrl);

    hipMemsetAsync(ctrl, 0, ctrl_bytes, stream);
    pack_weights<<<dim3(128), dim3(256), 0, stream>>>(Wf, Wi, Wg, Wo, ln_g, pack);
    compute_sc<<<dim3(8), dim3(256), 0, stream>>>(Wf, Wi, Wg, Wo, bf_, bi_, bg_, bo_,
                                                  ln_g, ln_b, S, C);
    prep_x<<<dim3(16384), dim3(256), 0, stream>>>(x, xb, sx, sq);
    qlstm_main<<<dim3(NWG), dim3(512), 0, stream>>>(x, pack, S, C, xb, sx, sq,
                                                    hxb, psc, flags, (float*)d_out);
}

// Round 6
// 8621.281 us; speedup vs baseline: 2.0422x; 2.0422x over previous
//
#include <hip/hip_runtime.h>
#include <hip/hip_bf16.h>

#define T_STEPS 1024
#define NWG     64

typedef __attribute__((ext_vector_type(8))) short          bf16x8;
typedef __attribute__((ext_vector_type(4))) float          f32x4;
typedef __attribute__((ext_vector_type(8))) unsigned short u16x8;

static __device__ __forceinline__ unsigned short f2bf_bits(float f) {
    union { __hip_bfloat16 h; unsigned short u; } cv;
    cv.h = __float2bfloat16(f);
    return cv.u;
}

// ---------------------------------------------------------------------------
// P1: fold ln_g into weights, cast bf16, emit in MFMA B-fragment order.
// Chunk layout: [g][part][tn][kstep][lane][e]
//   k  = part*512 + kstep*32 + (lane>>4)*8 + e
//   c  = tn*16 + (lane&15);  n = (c>>3)*512 + g*8 + (c&7)
// ---------------------------------------------------------------------------
__global__ __launch_bounds__(256) void pack_weights(
    const float* __restrict__ Wf, const float* __restrict__ Wi,
    const float* __restrict__ Wg, const float* __restrict__ Wo,
    const float* __restrict__ ln_g, __hip_bfloat16* __restrict__ pack)
{
    __shared__ unsigned short tile[512 * 32];   // [k_local][c]
    const int blk = blockIdx.x;
    const int g = blk >> 1, part = blk & 1;
    const int tid = threadIdx.x;

    for (int idx = tid; idx < 512 * 32; idx += 256) {
        int kl = idx >> 5, c = idx & 31;
        int q = c >> 3, jl = c & 7;
        int k = part * 512 + kl;
        const float* W = (q == 0) ? Wf : ((q == 1) ? Wi : ((q == 2) ? Wg : Wo));
        float v = W[k * 512 + g * 8 + jl] * ln_g[k];
        tile[kl * 32 + c] = f2bf_bits(v);
    }
    __syncthreads();

    unsigned short* out = (unsigned short*)(pack + (size_t)blk * 16384);
    for (int s = tid; s < 2048; s += 256) {        // slot = tn*1024 + ks*64 + l
        int tn = s >> 10, ks = (s >> 6) & 15, l = s & 63;
        u16x8 v;
#pragma unroll
        for (int e = 0; e < 8; ++e) {
            int klocal = ks * 32 + ((l >> 4) * 8) + e;
            int c = tn * 16 + (l & 15);
            v[e] = tile[klocal * 32 + c];
        }
        *(u16x8*)(out + (size_t)s * 8) = v;
    }
}

// ---------------------------------------------------------------------------
// P2: S[n] = sum_k ln_g[k]*W[k,n],  C[n] = sum_k ln_b[k]*W[k,n] + bias[n]
// ---------------------------------------------------------------------------
__global__ __launch_bounds__(256) void compute_sc(
    const float* __restrict__ Wf, const float* __restrict__ Wi,
    const float* __restrict__ Wg, const float* __restrict__ Wo,
    const float* __restrict__ bf_, const float* __restrict__ bi_,
    const float* __restrict__ bg_, const float* __restrict__ bo_,
    const float* __restrict__ ln_g, const float* __restrict__ ln_b,
    float* __restrict__ S, float* __restrict__ C)
{
    int n = blockIdx.x * 256 + threadIdx.x;        // 0..2047
    int q = n >> 9, j = n & 511;
    const float* W = (q == 0) ? Wf : ((q == 1) ? Wi : ((q == 2) ? Wg : Wo));
    const float* bb = (q == 0) ? bf_ : ((q == 1) ? bi_ : ((q == 2) ? bg_ : bo_));
    float accS = 0.f, accC = 0.f;
    for (int k = 0; k < 1024; ++k) {
        float w = W[k * 512 + j];
        accS += ln_g[k] * w;
        accC += ln_b[k] * w;
    }
    S[n] = accS;
    C[n] = accC + bb[j];
}

// ---------------------------------------------------------------------------
// P3: x -> bf16 copy + per-row sum / sumsq (fp32). One wave per (t,b) row.
// ---------------------------------------------------------------------------
__global__ __launch_bounds__(256) void prep_x(
    const float* __restrict__ x, __hip_bfloat16* __restrict__ xb,
    float* __restrict__ sx, float* __restrict__ sq)
{
    const int wave = threadIdx.x >> 6, lane = threadIdx.x & 63;
    const long row = (long)blockIdx.x * 4 + wave;  // 0..65535
    const float* src = x + row * 512 + lane * 8;
    float4 a = *(const float4*)src;
    float4 b = *(const float4*)(src + 4);
    float vals[8] = {a.x, a.y, a.z, a.w, b.x, b.y, b.z, b.w};
    u16x8 o;
    float s = 0.f, qq = 0.f;
#pragma unroll
    for (int e = 0; e < 8; ++e) {
        s += vals[e];
        qq += vals[e] * vals[e];
        o[e] = f2bf_bits(vals[e]);
    }
    *(u16x8*)((unsigned short*)xb + row * 512 + lane * 8) = o;
#pragma unroll
    for (int d = 1; d < 64; d <<= 1) {
        s  += __shfl_xor(s, d);
        qq += __shfl_xor(qq, d);
    }
    if (lane == 0) { sx[row] = s; sq[row] = qq; }
}

// ---------------------------------------------------------------------------
// Main persistent kernel: 64 WGs x 512 threads (R3 structure + 3 fixes).
// Wave w: m = w>>1 (16-row M tile), kh = w&1 (K half of the h part).
// Sync: per-(WG,wave) flags. Publish = sc1 stores + vmcnt(0) + lane0 flag.
// Spin: lane l polls the {2m,2m+1} flag pair of WG l with EXPONENTIAL
// s_sleep BACKOFF (fix 1: un-jam the fabric so the flag store can land).
// Stats: computed LOCALLY from the h fragments each wave loads anyway
// (fix 2: psc all-to-all deleted; VALU sums co-issue with MFMA pipe).
// x-GEMM A-frags for t+1 are register-prefetched BEFORE the spin
// (fix 3: HBM latency hides under the wait).
// Thread t: b = t>>3, jl = t&7 owns gate/state element (b, 8g+jl).
// ---------------------------------------------------------------------------
__global__ __launch_bounds__(512, 2) void qlstm_main(
    const float* __restrict__ x,
    const __hip_bfloat16* __restrict__ pack,
    const float* __restrict__ Sarr, const float* __restrict__ Carr,
    const __hip_bfloat16* __restrict__ xb,
    const float* __restrict__ sx, const float* __restrict__ sq,
    unsigned short* __restrict__ hxb,   // [2][64][512] bf16 (zeroed)
    unsigned int* __restrict__ flags,   // [64 WG][16 u32] = 64B/WG (zeroed)
    float* __restrict__ out)            // stacked | hx | cx (fp32)
{
    const int g = blockIdx.x;
    const int tid = threadIdx.x;
    const int wave = tid >> 6, lane = tid & 63;
    const int m = wave >> 1, kh = wave & 1;
    const int b = tid >> 3, jl = tid & 7, jg = g * 8 + jl;

    __shared__ float zXs[2][2][2112];          // [parity][kh][row*33+col]
    __shared__ float zHs[2][2112];             // [kh]
    __shared__ float rsS[64][2], rsQ[64][2];   // per-row h sum/sumsq, per kh
    __shared__ float Scol[32], Ccol[32];

    if (tid < 32) {
        int n = (tid >> 3) * 512 + g * 8 + (tid & 7);
        Scol[tid] = Sarr[n];
        Ccol[tid] = Carr[n];
    }

    // Persistent B-fragments: 4 x 8 frags x 4 VGPR = 128 regs.
    bf16x8 Bx0[8], Bx1[8], Bh0[8], Bh1[8];
    {
        const bf16x8* px = (const bf16x8*)(pack + (size_t)(g * 2 + 0) * 16384);
        const bf16x8* ph = (const bf16x8*)(pack + (size_t)(g * 2 + 1) * 16384);
#pragma unroll
        for (int i = 0; i < 8; ++i) {
            int ksp = kh * 8 + i;
            Bx0[i] = px[ksp * 64 + lane];
            Bx1[i] = px[1024 + ksp * 64 + lane];
            Bh0[i] = ph[ksp * 64 + lane];
            Bh1[i] = ph[1024 + ksp * 64 + lane];
        }
    }

    const int arow = m * 16 + (lane & 15);
    const int acol = (lane >> 4) * 8;
    const int r0 = m * 16 + (lane >> 4) * 4, c0 = lane & 15;
    float cx = 0.f;

    auto xgemm_store = [&](const bf16x8* af, int par) {
        f32x4 a0 = {0.f, 0.f, 0.f, 0.f}, a1 = {0.f, 0.f, 0.f, 0.f};
#pragma unroll
        for (int ks = 0; ks < 8; ++ks) {
            a0 = __builtin_amdgcn_mfma_f32_16x16x32_bf16(af[ks], Bx0[ks], a0, 0, 0, 0);
            a1 = __builtin_amdgcn_mfma_f32_16x16x32_bf16(af[ks], Bx1[ks], a1, 0, 0, 0);
        }
        float* zb = &zXs[par][kh][0];
#pragma unroll
        for (int r = 0; r < 4; ++r) {
            zb[(r0 + r) * 33 + c0]      = a0[r];
            zb[(r0 + r) * 33 + 16 + c0] = a1[r];
        }
    };

    // zX for t=0 (recurrence-independent)
    {
        const bf16x8* Ap = (const bf16x8*)(xb + (size_t)arow * 512 + kh * 256 + acol);
        bf16x8 af[8];
#pragma unroll
        for (int ks = 0; ks < 8; ++ks) af[ks] = Ap[ks * 4];
        xgemm_store(af, 0);
    }

    for (int t = 0; t < T_STEPS; ++t) {
        const int p = t & 1;

        // ---- recurrence-independent loads issued BEFORE the spin ----
        float xres = x[(size_t)t * 32768 + b * 512 + jg];
        float sxv = sx[t * 64 + b];
        float sqv = sq[t * 64 + b];
        bf16x8 afrN[8];                     // x A-frags for t+1 (fix 3)
        if (t + 1 < T_STEPS) {
            const bf16x8* Ap = (const bf16x8*)(xb + (size_t)(t + 1) * 32768
                                               + arow * 512 + kh * 256 + acol);
#pragma unroll
            for (int ks = 0; ks < 8; ++ks) afrN[ks] = Ap[ks * 4];
        }

        // ---- spin with exponential s_sleep backoff (fix 1) ----
        if (t) {
            const unsigned long long* fp_ =
                (const unsigned long long*)(flags + lane * 16 + m * 2);
            int slp = 0;
            for (;;) {
                unsigned long long v = __hip_atomic_load(fp_, __ATOMIC_RELAXED,
                                                         __HIP_MEMORY_SCOPE_AGENT);
                unsigned fa = (unsigned)v, fb = (unsigned)(v >> 32);
                unsigned mn = fa < fb ? fa : fb;
                if (__all((int)mn >= t)) break;
                if      (slp == 0) __builtin_amdgcn_s_sleep(1);
                else if (slp == 1) __builtin_amdgcn_s_sleep(2);
                else if (slp == 2) __builtin_amdgcn_s_sleep(4);
                else               __builtin_amdgcn_s_sleep(8);
                if (slp < 3) ++slp;
            }
            asm volatile("" ::: "memory");
        }

        // ---- coherent h A-frag loads (16 x 8B per lane, one RT) ----
        unsigned long long hlo[8], hhi[8];
        {
            const unsigned long long* hp =
                (const unsigned long long*)hxb + (size_t)p * 8192;
            const int ebase = (arow * 512 + kh * 256 + acol) >> 2;
#pragma unroll
            for (int ks = 0; ks < 8; ++ks) {
                hlo[ks] = __hip_atomic_load(hp + ebase + ks * 8, __ATOMIC_RELAXED,
                                            __HIP_MEMORY_SCOPE_AGENT);
                hhi[ks] = __hip_atomic_load(hp + ebase + ks * 8 + 1, __ATOMIC_RELAXED,
                                            __HIP_MEMORY_SCOPE_AGENT);
            }
        }

        // ---- h-GEMM (critical path) ----
        {
            f32x4 h0 = {0.f, 0.f, 0.f, 0.f}, h1 = {0.f, 0.f, 0.f, 0.f};
#pragma unroll
            for (int ks = 0; ks < 8; ++ks) {
                union { unsigned long long u[2]; bf16x8 v; } cv;
                cv.u[0] = hlo[ks]; cv.u[1] = hhi[ks];
                h0 = __builtin_amdgcn_mfma_f32_16x16x32_bf16(cv.v, Bh0[ks], h0, 0, 0, 0);
                h1 = __builtin_amdgcn_mfma_f32_16x16x32_bf16(cv.v, Bh1[ks], h1, 0, 0, 0);
            }
            float* zb = &zHs[kh][0];
#pragma unroll
            for (int r = 0; r < 4; ++r) {
                zb[(r0 + r) * 33 + c0]      = h0[r];
                zb[(r0 + r) * 33 + 16 + c0] = h1[r];
            }
        }

        // ---- local LN stats from the loaded h words (fix 2, VALU pipe) ----
        {
            float s = 0.f, q = 0.f;
#pragma unroll
            for (int ks = 0; ks < 8; ++ks) {
                unsigned uu[4] = { (unsigned)hlo[ks], (unsigned)(hlo[ks] >> 32),
                                   (unsigned)hhi[ks], (unsigned)(hhi[ks] >> 32) };
#pragma unroll
                for (int j = 0; j < 4; ++j) {
                    float f0 = __uint_as_float(uu[j] << 16);
                    float f1 = __uint_as_float(uu[j] & 0xffff0000u);
                    s += f0 + f1;
                    q = fmaf(f0, f0, q);
                    q = fmaf(f1, f1, q);
                }
            }
            // lanes {l, l^16, l^32, l^48} share arow
            s += __shfl_xor(s, 16); q += __shfl_xor(q, 16);
            s += __shfl_xor(s, 32); q += __shfl_xor(q, 32);
            if (lane < 16) { rsS[m * 16 + lane][kh] = s; rsQ[m * 16 + lane][kh] = q; }
        }
        __syncthreads();   // (A) zHs, rsS/rsQ, zXs[p] ready

        // ---- gates / state update (thread owns (b, jg)) ----
        float hval;
        {
            float hs = rsS[b][0] + rsS[b][1];
            float hq = rsQ[b][0] + rsQ[b][1];
            float mu = (sxv + hs) * (1.f / 1024.f);
            float var = (sqv + hq) * (1.f / 1024.f) - mu * mu;
            float rs = rsqrtf(var + 1e-5f);

            const float* zx0 = &zXs[p][0][0];
            const float* zx1 = &zXs[p][1][0];
            const float* zh0 = &zHs[0][0];
            const float* zh1 = &zHs[1][0];
            const int i0 = b * 33;
            float zf = zx0[i0 + jl]      + zx1[i0 + jl]      + zh0[i0 + jl]      + zh1[i0 + jl];
            float zi = zx0[i0 + 8 + jl]  + zx1[i0 + 8 + jl]  + zh0[i0 + 8 + jl]  + zh1[i0 + 8 + jl];
            float zg = zx0[i0 + 16 + jl] + zx1[i0 + 16 + jl] + zh0[i0 + 16 + jl] + zh1[i0 + 16 + jl];
            float zo = zx0[i0 + 24 + jl] + zx1[i0 + 24 + jl] + zh0[i0 + 24 + jl] + zh1[i0 + 24 + jl];
            zf = rs * (zf - mu * Scol[jl])      + Ccol[jl];
            zi = rs * (zi - mu * Scol[8 + jl])  + Ccol[8 + jl];
            zg = rs * (zg - mu * Scol[16 + jl]) + Ccol[16 + jl];
            zo = rs * (zo - mu * Scol[24 + jl]) + Ccol[24 + jl];

            float f  = 1.f / (1.f + __expf(-zf));
            float i_ = 1.f / (1.f + __expf(-zi));
            float gg = 2.f / (1.f + __expf(-2.f * zg)) - 1.f;
            float o_ = 1.f / (1.f + __expf(-zo));
            cx = f * cx + i_ * gg;
            float th = 2.f / (1.f + __expf(-2.f * cx)) - 1.f;
            hval = o_ * th + xres;
        }

        // ---- publish (sc1 write-through from registers) + per-wave flag ----
        if (t + 1 < T_STEPS) {
            unsigned hb = (unsigned)f2bf_bits(hval);
            unsigned v01 = hb | ((unsigned)__shfl_xor((int)hb, 1) << 16);
            unsigned long long v03 = (unsigned long long)v01 |
                ((unsigned long long)(unsigned)__shfl_xor((int)v01, 2) << 32);
            if ((jl & 3) == 0) {
                unsigned long long* hdst = (unsigned long long*)
                    (hxb + (size_t)(p ^ 1) * 32768 + b * 512 + g * 8 + jl);
                __hip_atomic_store(hdst, v03, __ATOMIC_RELAXED, __HIP_MEMORY_SCOPE_AGENT);
            }
            asm volatile("s_waitcnt vmcnt(0)" ::: "memory");
            if (lane == 0) {
                __hip_atomic_store(flags + g * 16 + wave, (unsigned)(t + 1),
                                   __ATOMIC_RELAXED, __HIP_MEMORY_SCOPE_AGENT);
            }
        }

        // ---- shadow: out writes ----
        out[(size_t)t * 32768 + b * 512 + jg] = hval;
        if (t == T_STEPS - 1) {
            out[(size_t)T_STEPS * 32768 + b * 512 + jg] = hval;
            out[(size_t)T_STEPS * 32768 + 32768 + b * 512 + jg] = cx;
        }

        __syncthreads();   // (B) zHs/rs*/zXs reuse guard

        // ---- x-GEMM for t+1 from prefetched regs (off critical path) ----
        if (t + 1 < T_STEPS) xgemm_store(afrN, p ^ 1);
    }
}

// ---------------------------------------------------------------------------
extern "C" void kernel_launch(void* const* d_in, const int* in_sizes, int n_in,
                              void* d_out, int out_size, void* d_ws, size_t ws_size,
                              hipStream_t stream)
{
    const float* x    = (const float*)d_in[0];
    const float* ln_g = (const float*)d_in[1];
    const float* ln_b = (const float*)d_in[2];
    const float* Wf   = (const float*)d_in[3];
    const float* bf_  = (const float*)d_in[4];
    const float* Wi   = (const float*)d_in[5];
    const float* bi_  = (const float*)d_in[6];
    const float* Wg   = (const float*)d_in[7];
    const float* bg_  = (const float*)d_in[8];
    const float* Wo   = (const float*)d_in[9];
    const float* bo_  = (const float*)d_in[10];

    char* ws = (char*)d_ws;
    size_t off = 0;
    auto take = [&](size_t bytes) -> char* {
        char* p = ws + off;
        off += (bytes + 255) & ~(size_t)255;
        return p;
    };
    __hip_bfloat16* pack = (__hip_bfloat16*)take((size_t)2097152 * 2); // 4 MB
    float* S             = (float*)take(2048 * 4);
    float* C             = (float*)take(2048 * 4);
    __hip_bfloat16* xb   = (__hip_bfloat16*)take((size_t)33554432 * 2); // 64 MB
    float* sx            = (float*)take(65536 * 4);
    float* sq            = (float*)take(65536 * 4);
    char* ctrl = ws + off;
    unsigned short* hxb  = (unsigned short*)take((size_t)2 * 64 * 512 * 2); // 128 KB
    unsigned int* flags  = (unsigned int*)take(64 * 64);                    // 4 KB
    size_t ctrl_bytes = (size_t)((ws + off) - ctrl);

    hipMemsetAsync(ctrl, 0, ctrl_bytes, stream);
    pack_weights<<<dim3(128), dim3(256), 0, stream>>>(Wf, Wi, Wg, Wo, ln_g, pack);
    compute_sc<<<dim3(8), dim3(256), 0, stream>>>(Wf, Wi, Wg, Wo, bf_, bi_, bg_, bo_,
                                                  ln_g, ln_b, S, C);
    prep_x<<<dim3(16384), dim3(256), 0, stream>>>(x, xb, sx, sq);
    qlstm_main<<<dim3(NWG), dim3(512), 0, stream>>>(x, pack, S, C, xb, sx, sq,
                                                    hxb, flags, (float*)d_out);
}